// Round 2
// baseline (285.973 us; speedup 1.0000x reference)
//
#include <hip/hip_runtime.h>
#include <hip/hip_bf16.h>
#include <stdint.h>

// ---------------------------------------------------------------------------
// BinaryMLP fused kernel, round 2: barrier-free K-loops.
// - B-fragments (binarized weights, +-1 exact in bf16) are loaded DIRECTLY
//   from global memory (L2-hot, prep kernel lays them out in MFMA fragment
//   order) -> no W staging in LDS, no per-K-step barriers.
// - Layer-1 A-fragments load directly from x (f32, HBM) and convert in regs.
// - LDS holds only the 128x512 bf16 activation tile H (XOR-swizzled);
//   it is read-only during K-loops, so barriers exist only around epilogues.
// - Register ping-pong prefetch (static names, no runtime-indexed arrays).
// ---------------------------------------------------------------------------

typedef __attribute__((ext_vector_type(8))) short short8;   // 8 bf16
typedef __attribute__((ext_vector_type(4))) float f32x4;    // MFMA accum

#define THREADS 512
#define BM      128
#define HID     512
#define K1      784
#define K1P     800
#define BK      32
#define NK1     (K1P / BK)      // 25
#define NK2     (HID / BK)      // 16
#define WCHUNK  (HID * BK * 2)  // 32768 B : one K-tile of a 512-row weight panel

#define W1_OFF  0
#define W1_BYTES (NK1 * WCHUNK)             // 819200
#define W2_OFF  (W1_OFF + W1_BYTES)
#define W2_BYTES (NK2 * WCHUNK)             // 524288
#define W3_OFF  (W2_OFF + W2_BYTES)
#define W4_OFF  (W3_OFF + W2_BYTES)
#define W4_BYTES (16 * HID * 2)             // 16384 (rows 10..15 zero)
#define WS_BYTES (W4_OFF + W4_BYTES)        // 1884160

#define LDS_TOTAL (BM * HID * 2)            // 131072 : H tile only

__device__ __forceinline__ unsigned short bfu(float f) {
    __hip_bfloat16 h = __float2bfloat16(f);
    return *reinterpret_cast<unsigned short*>(&h);
}

__device__ __forceinline__ short8 cvt8(float4 a, float4 b) {
    short8 r;
    r[0] = (short)bfu(a.x); r[1] = (short)bfu(a.y);
    r[2] = (short)bfu(a.z); r[3] = (short)bfu(a.w);
    r[4] = (short)bfu(b.x); r[5] = (short)bfu(b.y);
    r[6] = (short)bfu(b.z); r[7] = (short)bfu(b.w);
    return r;
}

// ---------------------------------------------------------------------------
// prep: binarize/convert weights into ws in per-K-tile [n][kk] row-major
// chunks (exactly MFMA B-fragment order, 16B-aligned). Each thread handles
// 16 consecutive k's of one row: 64B coalesced read, 32B coalesced write.
// ---------------------------------------------------------------------------
__global__ void prep_weights(const float* __restrict__ w1, const float* __restrict__ w2,
                             const float* __restrict__ w3, const float* __restrict__ w4,
                             unsigned char* __restrict__ ws)
{
    int id = blockIdx.x * blockDim.x + threadIdx.x;
    const int T1 = HID * (K1P / 16);    // 25600
    const int T2 = HID * (HID / 16);    // 16384
    const int T4 = 16 * (HID / 16);     // 512

    unsigned short v[16];

    if (id < T1) {
        int n = id / (K1P / 16), j = id % (K1P / 16);
        int kp0 = j * 16;
#pragma unroll
        for (int i = 0; i < 16; ++i) {
            int kp = kp0 + i;
            v[i] = (kp < K1) ? ((w1[n * K1 + kp] >= 0.0f) ? 0x3F80u : 0xBF80u) : 0;
        }
        unsigned off = W1_OFF + (kp0 >> 5) * WCHUNK + n * 64 + (kp0 & 31) * 2;
        *(short8*)(ws + off)      = *(short8*)&v[0];
        *(short8*)(ws + off + 16) = *(short8*)&v[8];
        return;
    }
    id -= T1;
    if (id < T2) {
        int n = id / (HID / 16), j = id % (HID / 16);
        int kp0 = j * 16;
#pragma unroll
        for (int i = 0; i < 16; ++i)
            v[i] = (w2[n * HID + kp0 + i] >= 0.0f) ? 0x3F80u : 0xBF80u;
        unsigned off = W2_OFF + (kp0 >> 5) * WCHUNK + n * 64 + (kp0 & 31) * 2;
        *(short8*)(ws + off)      = *(short8*)&v[0];
        *(short8*)(ws + off + 16) = *(short8*)&v[8];
        return;
    }
    id -= T2;
    if (id < T2) {
        int n = id / (HID / 16), j = id % (HID / 16);
        int kp0 = j * 16;
#pragma unroll
        for (int i = 0; i < 16; ++i)
            v[i] = (w3[n * HID + kp0 + i] >= 0.0f) ? 0x3F80u : 0xBF80u;
        unsigned off = W3_OFF + (kp0 >> 5) * WCHUNK + n * 64 + (kp0 & 31) * 2;
        *(short8*)(ws + off)      = *(short8*)&v[0];
        *(short8*)(ws + off + 16) = *(short8*)&v[8];
        return;
    }
    id -= T2;
    if (id < T4) {
        int n = id / (HID / 16), j = id % (HID / 16);
        int kp0 = j * 16;
#pragma unroll
        for (int i = 0; i < 16; ++i)
            v[i] = (n < 10) ? bfu(w4[n * HID + kp0 + i]) : 0;
        unsigned off = W4_OFF + n * 1024 + kp0 * 2;   // plain [16][512]
        *(short8*)(ws + off)      = *(short8*)&v[0];
        *(short8*)(ws + off + 16) = *(short8*)&v[8];
    }
}

// ---------------------------------------------------------------------------
// fused MLP: 1 block = 128 batch rows, 8 waves (2 M x 4 N), mfma 16x16x32 bf16
// ---------------------------------------------------------------------------
__global__ __launch_bounds__(THREADS, 2)
void fused_mlp(const float* __restrict__ x,
               const unsigned char* __restrict__ ws,
               const float* __restrict__ b1, const float* __restrict__ b2,
               const float* __restrict__ b3, const float* __restrict__ b4,
               float* __restrict__ out)
{
    extern __shared__ unsigned char lds[];
    const int tid  = threadIdx.x;
    const int lane = tid & 63;
    const int wave = tid >> 6;
    const int wm   = wave >> 2;          // 0..1  (64 rows each)
    const int wn   = wave & 3;           // 0..3  (128 cols each)
    const int lr   = lane & 15;
    const int lg   = lane >> 4;
    const int row_base = blockIdx.x * BM;

    // epilogue: acc -> relu(acc+bias) -> bf16 -> H (swizzled). callers barrier.
    auto epilogueToH = [&](f32x4 (&acc)[4][8], const float* __restrict__ bias) {
#pragma unroll
        for (int nf = 0; nf < 8; ++nf) {
            int col = wn * 128 + nf * 16 + lr;
            float bv = bias[col];
#pragma unroll
            for (int mf = 0; mf < 4; ++mf) {
#pragma unroll
                for (int r = 0; r < 4; ++r) {
                    int row = wm * 64 + mf * 16 + lg * 4 + r;
                    float vv = acc[mf][nf][r] + bv;
                    vv = vv > 0.0f ? vv : 0.0f;
                    unsigned off = ((unsigned)(row * 1024 + col * 2)) ^ (unsigned)((row & 7) << 4);
                    *(unsigned short*)(lds + off) = bfu(vv);
                }
            }
        }
    };

    // ---------------- Layer 1: x(f32 global) -> h1, no LDS in K-loop -------
    {
        f32x4 acc[4][8];
#pragma unroll
        for (int mf = 0; mf < 4; ++mf)
#pragma unroll
            for (int nf = 0; nf < 8; ++nf)
                acc[mf][nf] = (f32x4){0.f, 0.f, 0.f, 0.f};

        const float* xp0 = x + (size_t)(row_base + wm * 64 +  0 + lr) * K1;
        const float* xp1 = x + (size_t)(row_base + wm * 64 + 16 + lr) * K1;
        const float* xp2 = x + (size_t)(row_base + wm * 64 + 32 + lr) * K1;
        const float* xp3 = x + (size_t)(row_base + wm * 64 + 48 + lr) * K1;
        const unsigned char* wB1 = ws + W1_OFF + wn * 8192 + lr * 64 + lg * 16;

        float4 xa[4][2], xb[4][2];

        auto l1_load = [&](float4 (&XR)[4][2], int kt) {
            int k0 = kt * BK + lg * 8;
            if (k0 < K1) {
                XR[0][0] = *(const float4*)(xp0 + k0); XR[0][1] = *(const float4*)(xp0 + k0 + 4);
                XR[1][0] = *(const float4*)(xp1 + k0); XR[1][1] = *(const float4*)(xp1 + k0 + 4);
                XR[2][0] = *(const float4*)(xp2 + k0); XR[2][1] = *(const float4*)(xp2 + k0 + 4);
                XR[3][0] = *(const float4*)(xp3 + k0); XR[3][1] = *(const float4*)(xp3 + k0 + 4);
            } else {
                float4 z = make_float4(0.f, 0.f, 0.f, 0.f);
#pragma unroll
                for (int mf = 0; mf < 4; ++mf) { XR[mf][0] = z; XR[mf][1] = z; }
            }
        };

        auto l1_step = [&](float4 (&XR)[4][2], int kt) {
            const unsigned char* bb = wB1 + (size_t)kt * WCHUNK;
            short8 bf[8];
#pragma unroll
            for (int nf = 0; nf < 8; ++nf)
                bf[nf] = *(const short8*)(bb + nf * 1024);
            short8 a[4];
#pragma unroll
            for (int mf = 0; mf < 4; ++mf)
                a[mf] = cvt8(XR[mf][0], XR[mf][1]);
            // nf-outer: first MFMAs only need bf[0] (oldest outstanding load)
#pragma unroll
            for (int nf = 0; nf < 8; ++nf)
#pragma unroll
                for (int mf = 0; mf < 4; ++mf)
                    acc[mf][nf] = __builtin_amdgcn_mfma_f32_16x16x32_bf16(a[mf], bf[nf], acc[mf][nf], 0, 0, 0);
        };

        l1_load(xa, 0);
#pragma unroll 1
        for (int kt = 0; kt < 24; kt += 2) {
            l1_load(xb, kt + 1);
            l1_step(xa, kt);
            l1_load(xa, kt + 2);          // kt+2 <= 24 (kt==24 load has zero-fill tail)
            l1_step(xb, kt + 1);
        }
        l1_step(xa, 24);

        __syncthreads();
        epilogueToH(acc, b1);
        __syncthreads();
    }

    // ---------------- Layers 2 & 3: A from LDS-H, B from global ------------
#pragma unroll 1
    for (int layer = 0; layer < 2; ++layer) {
        const unsigned char* wb = ws + (layer == 0 ? W2_OFF : W3_OFF)
                                + wn * 8192 + lr * 64 + lg * 16;
        const float* bias = (layer == 0) ? b2 : b3;

        f32x4 acc[4][8];
#pragma unroll
        for (int mf = 0; mf < 4; ++mf)
#pragma unroll
            for (int nf = 0; nf < 8; ++nf)
                acc[mf][nf] = (f32x4){0.f, 0.f, 0.f, 0.f};

        short8 p0[8], p1[8];

        auto loadB = [&](short8 (&P)[8], int kt) {
            const unsigned char* bb = wb + (size_t)kt * WCHUNK;
#pragma unroll
            for (int nf = 0; nf < 8; ++nf)
                P[nf] = *(const short8*)(bb + nf * 1024);
        };

        auto l23_step = [&](short8 (&P)[8], int kt) {
            short8 a[4];
#pragma unroll
            for (int mf = 0; mf < 4; ++mf) {
                int m = wm * 64 + mf * 16 + lr;
                unsigned off = ((unsigned)(m * 1024 + kt * 64 + lg * 16)) ^ (unsigned)((m & 7) << 4);
                a[mf] = *(const short8*)(lds + off);
            }
            // mf-outer: first MFMAs only need a[0] (B already in regs)
#pragma unroll
            for (int mf = 0; mf < 4; ++mf)
#pragma unroll
                for (int nf = 0; nf < 8; ++nf)
                    acc[mf][nf] = __builtin_amdgcn_mfma_f32_16x16x32_bf16(a[mf], P[nf], acc[mf][nf], 0, 0, 0);
        };

        loadB(p0, 0);
#pragma unroll 1
        for (int kt = 0; kt < NK2; kt += 2) {
            loadB(p1, kt + 1);
            l23_step(p0, kt);
            if (kt + 2 < NK2) loadB(p0, kt + 2);
            l23_step(p1, kt + 1);
        }

        __syncthreads();           // all H reads done
        epilogueToH(acc, bias);    // in-place overwrite of H
        __syncthreads();           // new H visible
    }

    // ---------------- Layer 4: h3 @ w4^T (16-col padded, 10 real) ----------
    {
        const unsigned char* w4b = ws + W4_OFF + lr * 1024 + lg * 16;
        const int m = wave * 16 + lr;
        f32x4 acc = (f32x4){0.f, 0.f, 0.f, 0.f};
#pragma unroll
        for (int kt = 0; kt < NK2; ++kt) {
            unsigned aoff = ((unsigned)(m * 1024 + kt * 64 + lg * 16)) ^ (unsigned)((m & 7) << 4);
            short8 a = *(const short8*)(lds + aoff);
            short8 b = *(const short8*)(w4b + kt * 64);
            acc = __builtin_amdgcn_mfma_f32_16x16x32_bf16(a, b, acc, 0, 0, 0);
        }
        int o = lr;
        if (o < 10) {
            float bv = b4[o];
#pragma unroll
            for (int r = 0; r < 4; ++r) {
                int row = row_base + wave * 16 + lg * 4 + r;
                out[(size_t)row * 10 + o] = acc[r] + bv;
            }
        }
    }
}

extern "C" void kernel_launch(void* const* d_in, const int* in_sizes, int n_in,
                              void* d_out, int out_size, void* d_ws, size_t ws_size,
                              hipStream_t stream) {
    const float* x  = (const float*)d_in[0];
    const float* w1 = (const float*)d_in[1];
    const float* b1 = (const float*)d_in[2];
    const float* w2 = (const float*)d_in[3];
    const float* b2 = (const float*)d_in[4];
    const float* w3 = (const float*)d_in[5];
    const float* b3 = (const float*)d_in[6];
    const float* w4 = (const float*)d_in[7];
    const float* b4 = (const float*)d_in[8];
    float* out = (float*)d_out;
    unsigned char* ws = (unsigned char*)d_ws;

    if (ws_size < (size_t)WS_BYTES) return;

    const int B = in_sizes[0] / K1;           // 65536
    const int nblk = B / BM;                  // 512

    (void)hipFuncSetAttribute((const void*)fused_mlp,
                              hipFuncAttributeMaxDynamicSharedMemorySize, LDS_TOTAL);

    const int prep_total = HID * (K1P / 16) + 2 * HID * (HID / 16) + 16 * (HID / 16);
    prep_weights<<<(prep_total + 255) / 256, 256, 0, stream>>>(w1, w2, w3, w4, ws);
    fused_mlp<<<nblk, THREADS, LDS_TOTAL, stream>>>(x, ws, b1, b2, b3, b4, out);
}

// Round 3
// 215.041 us; speedup vs baseline: 1.3299x; 1.3299x over previous
//
#include <hip/hip_runtime.h>
#include <hip/hip_bf16.h>
#include <stdint.h>

// ---------------------------------------------------------------------------
// BinaryMLP fused, round 3: occupancy-first.
// BM=64 rows/block -> LDS = 64KB H + 8KB x-dbuf = 72KB -> 2 blocks/CU
// (16 waves/CU, 4/SIMD). 8 waves each own a 64x64 output tile (1Mx8N):
// acc[4][4], zero B-fragment redundancy across waves.
// W: direct from global (L2-hot, prep writes MFMA-fragment order).
// Layer 1: x staged coalesced f32->bf16 through LDS dbuf (issue-early /
// write-late, T14). Layers 2/3: barrier-free K-loops (A from read-only H).
// ---------------------------------------------------------------------------

typedef __attribute__((ext_vector_type(8))) short short8;   // 8 bf16
typedef __attribute__((ext_vector_type(4))) float f32x4;    // MFMA accum

#define THREADS 512
#define BM      64
#define HID     512
#define K1      784
#define K1P     800
#define BK      32
#define NK1     (K1P / BK)      // 25
#define NK2     (HID / BK)      // 16
#define WCHUNK  (HID * BK * 2)  // 32768 B : one K-tile of a 512-row weight panel

#define W1_OFF  0
#define W1_BYTES (NK1 * WCHUNK)             // 819200
#define W2_OFF  (W1_OFF + W1_BYTES)
#define W2_BYTES (NK2 * WCHUNK)             // 524288
#define W3_OFF  (W2_OFF + W2_BYTES)
#define W4_OFF  (W3_OFF + W2_BYTES)
#define W4_BYTES (16 * HID * 2)             // 16384 (rows 10..15 zero)
#define WS_BYTES (W4_OFF + W4_BYTES)        // 1884160

#define H_BYTES  (BM * HID * 2)             // 65536
#define XBUF0    H_BYTES
#define XBUF_SZ  (BM * BK * 2)              // 4096
#define LDS_TOTAL (H_BYTES + 2 * XBUF_SZ)   // 73728

__device__ __forceinline__ unsigned short bfu(float f) {
    __hip_bfloat16 h = __float2bfloat16(f);
    return *reinterpret_cast<unsigned short*>(&h);
}

// ---------------------------------------------------------------------------
// prep: binarize/convert weights into ws, per-K-tile [n][kk] row-major chunks
// (exact MFMA B-fragment order, n-stride 64B). Coalesced 64B reads/32B writes.
// ---------------------------------------------------------------------------
__global__ void prep_weights(const float* __restrict__ w1, const float* __restrict__ w2,
                             const float* __restrict__ w3, const float* __restrict__ w4,
                             unsigned char* __restrict__ ws)
{
    int id = blockIdx.x * blockDim.x + threadIdx.x;
    const int T1 = HID * (K1P / 16);    // 25600
    const int T2 = HID * (HID / 16);    // 16384
    const int T4 = 16 * (HID / 16);     // 512

    unsigned short v[16];

    if (id < T1) {
        int n = id / (K1P / 16), j = id % (K1P / 16);
        int kp0 = j * 16;
#pragma unroll
        for (int i = 0; i < 16; ++i) {
            int kp = kp0 + i;
            v[i] = (kp < K1) ? ((w1[n * K1 + kp] >= 0.0f) ? 0x3F80u : 0xBF80u) : 0;
        }
        unsigned off = W1_OFF + (kp0 >> 5) * WCHUNK + n * 64 + (kp0 & 31) * 2;
        *(short8*)(ws + off)      = *(short8*)&v[0];
        *(short8*)(ws + off + 16) = *(short8*)&v[8];
        return;
    }
    id -= T1;
    if (id < T2) {
        int n = id / (HID / 16), j = id % (HID / 16);
        int kp0 = j * 16;
#pragma unroll
        for (int i = 0; i < 16; ++i)
            v[i] = (w2[n * HID + kp0 + i] >= 0.0f) ? 0x3F80u : 0xBF80u;
        unsigned off = W2_OFF + (kp0 >> 5) * WCHUNK + n * 64 + (kp0 & 31) * 2;
        *(short8*)(ws + off)      = *(short8*)&v[0];
        *(short8*)(ws + off + 16) = *(short8*)&v[8];
        return;
    }
    id -= T2;
    if (id < T2) {
        int n = id / (HID / 16), j = id % (HID / 16);
        int kp0 = j * 16;
#pragma unroll
        for (int i = 0; i < 16; ++i)
            v[i] = (w3[n * HID + kp0 + i] >= 0.0f) ? 0x3F80u : 0xBF80u;
        unsigned off = W3_OFF + (kp0 >> 5) * WCHUNK + n * 64 + (kp0 & 31) * 2;
        *(short8*)(ws + off)      = *(short8*)&v[0];
        *(short8*)(ws + off + 16) = *(short8*)&v[8];
        return;
    }
    id -= T2;
    if (id < T4) {
        int n = id / (HID / 16), j = id % (HID / 16);
        int kp0 = j * 16;
#pragma unroll
        for (int i = 0; i < 16; ++i)
            v[i] = (n < 10) ? bfu(w4[n * HID + kp0 + i]) : 0;
        unsigned off = W4_OFF + n * 1024 + kp0 * 2;   // plain [16][512]
        *(short8*)(ws + off)      = *(short8*)&v[0];
        *(short8*)(ws + off + 16) = *(short8*)&v[8];
    }
}

// ---------------------------------------------------------------------------
// fused MLP: 1 block = 64 batch rows, 8 waves each owning 64x64 output
// ---------------------------------------------------------------------------
__global__ __launch_bounds__(THREADS, 4)
void fused_mlp(const float* __restrict__ x,
               const unsigned char* __restrict__ ws,
               const float* __restrict__ b1, const float* __restrict__ b2,
               const float* __restrict__ b3, const float* __restrict__ b4,
               float* __restrict__ out)
{
    extern __shared__ unsigned char lds[];
    const int tid  = threadIdx.x;
    const int lane = tid & 63;
    const int wave = tid >> 6;           // 0..7 : N-slice of 64 cols
    const int lr   = lane & 15;
    const int lg   = lane >> 4;
    const int row_base = blockIdx.x * BM;

    // H (swizzled) byte offset for (row, byte-col)
    auto h_off = [&](int row, int bc) -> unsigned {
        return ((unsigned)(row * 1024 + bc)) ^ (unsigned)((row & 7) << 4);
    };
    // xbuf (swizzled) byte offset
    auto x_off = [&](int buf, int row, int bc) -> unsigned {
        return XBUF0 + buf * XBUF_SZ
             + (((unsigned)(row * 64 + bc)) ^ (unsigned)((row & 7) << 4));
    };

    // epilogue: acc -> relu(acc+bias) -> bf16 -> H (swizzled)
    auto epilogueToH = [&](f32x4 (&acc)[4][4], const float* __restrict__ bias) {
#pragma unroll
        for (int nf = 0; nf < 4; ++nf) {
            int col = wave * 64 + nf * 16 + lr;
            float bv = bias[col];
#pragma unroll
            for (int mf = 0; mf < 4; ++mf) {
#pragma unroll
                for (int r = 0; r < 4; ++r) {
                    int row = mf * 16 + lg * 4 + r;
                    float vv = acc[mf][nf][r] + bv;
                    vv = vv > 0.0f ? vv : 0.0f;
                    *(unsigned short*)(lds + h_off(row, col * 2)) = bfu(vv);
                }
            }
        }
    };

    // ---------------- Layer 1: x (staged via LDS dbuf) -> h1 ----------------
    {
        f32x4 acc[4][4];
#pragma unroll
        for (int mf = 0; mf < 4; ++mf)
#pragma unroll
            for (int nf = 0; nf < 4; ++nf)
                acc[mf][nf] = (f32x4){0.f, 0.f, 0.f, 0.f};

        const unsigned char* wB1 = ws + W1_OFF + wave * 4096 + lr * 64 + lg * 16;
        const int srow = tid >> 3, sq = tid & 7;   // staging: 8 lanes/row
        const float* xrow = x + (size_t)(row_base + srow) * K1;

        short8 pA[4], pB[4];

        auto loadB = [&](short8 (&P)[4], const unsigned char* base, int kt) {
            const unsigned char* bb = base + (size_t)kt * WCHUNK;
#pragma unroll
            for (int nf = 0; nf < 4; ++nf)
                P[nf] = *(const short8*)(bb + nf * 1024);
        };

        auto stage_load = [&](int kt) -> float4 {
            int col = kt * BK + sq * 4;
            return (col < K1) ? *(const float4*)(xrow + col)
                              : make_float4(0.f, 0.f, 0.f, 0.f);
        };
        auto stage_write = [&](int buf, float4 v) {
            uint2 pk;
            pk.x = (unsigned)bfu(v.x) | ((unsigned)bfu(v.y) << 16);
            pk.y = (unsigned)bfu(v.z) | ((unsigned)bfu(v.w) << 16);
            *(uint2*)(lds + x_off(buf, srow, sq * 8)) = pk;
        };

        auto l1_step = [&](int buf, short8 (&P)[4]) {
            short8 a[4];
#pragma unroll
            for (int mf = 0; mf < 4; ++mf) {
                int row = mf * 16 + lr;
                a[mf] = *(const short8*)(lds + x_off(buf, row, lg * 16));
            }
#pragma unroll
            for (int mf = 0; mf < 4; ++mf)
#pragma unroll
                for (int nf = 0; nf < 4; ++nf)
                    acc[mf][nf] = __builtin_amdgcn_mfma_f32_16x16x32_bf16(a[mf], P[nf], acc[mf][nf], 0, 0, 0);
        };

        // prologue
        stage_write(0, stage_load(0));
        loadB(pA, wB1, 0);
        __syncthreads();

#pragma unroll 1
        for (int kt = 0; kt < NK1 - 1; kt += 2) {
            // even step
            float4 xv = stage_load(kt + 1);
            loadB(pB, wB1, kt + 1);
            l1_step(kt & 1, pA);           // buf0
            stage_write((kt + 1) & 1, xv); // buf1
            __syncthreads();
            // odd step
            bool more = (kt + 2 < NK1);
            float4 xv2 = more ? stage_load(kt + 2) : make_float4(0.f,0.f,0.f,0.f);
            if (more) loadB(pA, wB1, kt + 2);
            l1_step((kt + 1) & 1, pB);
            if (more) stage_write(kt & 1, xv2);
            __syncthreads();
        }
        l1_step(0, pA);                    // kt = 24 (buf 24&1 = 0)

        epilogueToH(acc, b1);              // H region untouched until now
        __syncthreads();
    }

    // ---------------- Layers 2 & 3: A from H (read-only), B from L2 --------
#pragma unroll 1
    for (int layer = 0; layer < 2; ++layer) {
        const unsigned char* wb = ws + (layer == 0 ? W2_OFF : W3_OFF)
                                + wave * 4096 + lr * 64 + lg * 16;
        const float* bias = (layer == 0) ? b2 : b3;

        f32x4 acc[4][4];
#pragma unroll
        for (int mf = 0; mf < 4; ++mf)
#pragma unroll
            for (int nf = 0; nf < 4; ++nf)
                acc[mf][nf] = (f32x4){0.f, 0.f, 0.f, 0.f};

        short8 pA[4], pB[4];

        auto loadB = [&](short8 (&P)[4], int kt) {
            const unsigned char* bb = wb + (size_t)kt * WCHUNK;
#pragma unroll
            for (int nf = 0; nf < 4; ++nf)
                P[nf] = *(const short8*)(bb + nf * 1024);
        };

        auto l23_step = [&](short8 (&P)[4], int kt) {
            short8 a[4];
#pragma unroll
            for (int mf = 0; mf < 4; ++mf) {
                int row = mf * 16 + lr;
                a[mf] = *(const short8*)(lds + h_off(row, kt * 64 + lg * 16));
            }
#pragma unroll
            for (int mf = 0; mf < 4; ++mf)
#pragma unroll
                for (int nf = 0; nf < 4; ++nf)
                    acc[mf][nf] = __builtin_amdgcn_mfma_f32_16x16x32_bf16(a[mf], P[nf], acc[mf][nf], 0, 0, 0);
        };

        loadB(pA, 0);
#pragma unroll 1
        for (int kt = 0; kt < NK2; kt += 2) {
            loadB(pB, kt + 1);
            l23_step(pA, kt);
            if (kt + 2 < NK2) loadB(pA, kt + 2);
            l23_step(pB, kt + 1);
        }

        __syncthreads();           // all H reads done before overwrite
        epilogueToH(acc, bias);
        __syncthreads();
    }

    // ---------------- Layer 4: h3 @ w4^T (16-col padded, 10 real) ----------
    if (wave < 4) {
        const unsigned char* w4b = ws + W4_OFF + lr * 1024 + lg * 16;
        const int m = wave * 16 + lr;
        f32x4 acc = (f32x4){0.f, 0.f, 0.f, 0.f};
#pragma unroll
        for (int kt = 0; kt < NK2; ++kt) {
            short8 a = *(const short8*)(lds + h_off(m, kt * 64 + lg * 16));
            short8 b = *(const short8*)(w4b + kt * 64);
            acc = __builtin_amdgcn_mfma_f32_16x16x32_bf16(a, b, acc, 0, 0, 0);
        }
        if (lr < 10) {
            float bv = b4[lr];
#pragma unroll
            for (int r = 0; r < 4; ++r) {
                int row = row_base + wave * 16 + lg * 4 + r;
                out[(size_t)row * 10 + lr] = acc[r] + bv;
            }
        }
    }
}

extern "C" void kernel_launch(void* const* d_in, const int* in_sizes, int n_in,
                              void* d_out, int out_size, void* d_ws, size_t ws_size,
                              hipStream_t stream) {
    const float* x  = (const float*)d_in[0];
    const float* w1 = (const float*)d_in[1];
    const float* b1 = (const float*)d_in[2];
    const float* w2 = (const float*)d_in[3];
    const float* b2 = (const float*)d_in[4];
    const float* w3 = (const float*)d_in[5];
    const float* b3 = (const float*)d_in[6];
    const float* w4 = (const float*)d_in[7];
    const float* b4 = (const float*)d_in[8];
    float* out = (float*)d_out;
    unsigned char* ws = (unsigned char*)d_ws;

    if (ws_size < (size_t)WS_BYTES) return;

    const int B = in_sizes[0] / K1;           // 65536
    const int nblk = B / BM;                  // 1024

    (void)hipFuncSetAttribute((const void*)fused_mlp,
                              hipFuncAttributeMaxDynamicSharedMemorySize, LDS_TOTAL);

    const int prep_total = HID * (K1P / 16) + 2 * HID * (HID / 16) + 16 * (HID / 16);
    prep_weights<<<(prep_total + 255) / 256, 256, 0, stream>>>(w1, w2, w3, w4, ws);
    fused_mlp<<<nblk, THREADS, LDS_TOTAL, stream>>>(x, ws, b1, b2, b3, b4, out);
}